// Round 6
// baseline (1104.594 us; speedup 1.0000x reference)
//
#include <hip/hip_runtime.h>
#include <hip/hip_bf16.h>

typedef __bf16 bf16x8 __attribute__((ext_vector_type(8)));
typedef float  f32x4  __attribute__((ext_vector_type(4)));
typedef unsigned int u32;

// async global->LDS, 16B/lane; LDS dest = wave-uniform base + lane*16 (m97/m104)
#define GLD_LDS16(gp, lp) __builtin_amdgcn_global_load_lds( \
    (const __attribute__((address_space(1))) u32*)(gp), \
    (__attribute__((address_space(3))) u32*)(lp), 16, 0, 0)

// DPP cyclic rotate within 16-lane rows (row_ror:N = 0x120|N) — VALU-pipe cross-lane
template<int CTRL>
__device__ __forceinline__ float dpp_rot(float x) {
    int y = __builtin_amdgcn_update_dpp(__float_as_int(x), __float_as_int(x),
                                        CTRL, 0xF, 0xF, false);
    return __int_as_float(y);
}
__device__ __forceinline__ float rowmax16(float x) {
    x = fmaxf(x, dpp_rot<0x121>(x));
    x = fmaxf(x, dpp_rot<0x122>(x));
    x = fmaxf(x, dpp_rot<0x124>(x));
    x = fmaxf(x, dpp_rot<0x128>(x));
    return x;
}
__device__ __forceinline__ float rowsum16(float x) {
    x += dpp_rot<0x121>(x);
    x += dpp_rot<0x122>(x);
    x += dpp_rot<0x124>(x);
    x += dpp_rot<0x128>(x);
    return x;
}

// ---------------------------------------------------------------- converts

__global__ __launch_bounds__(256) void f32_to_bf16_kernel(
    const float* __restrict__ in, __bf16* __restrict__ out, size_t n) {
    size_t i = ((size_t)blockIdx.x * 256 + threadIdx.x) * 8;
    if (i >= n) return;
    float4 a = *(const float4*)(in + i);
    float4 b = *(const float4*)(in + i + 4);
    bf16x8 v;
    v[0] = (__bf16)a.x; v[1] = (__bf16)a.y; v[2] = (__bf16)a.z; v[3] = (__bf16)a.w;
    v[4] = (__bf16)b.x; v[5] = (__bf16)b.y; v[6] = (__bf16)b.z; v[7] = (__bf16)b.w;
    *(bf16x8*)(out + i) = v;
}

// W[K][N] fp32  ->  Wt[N][K] bf16   (32x32 LDS tile transpose)
__global__ __launch_bounds__(256) void transpose_to_bf16_kernel(
    const float* __restrict__ W, __bf16* __restrict__ Wt, int K, int N) {
    __shared__ float tile[32][33];
    int n0 = blockIdx.x * 32, k0 = blockIdx.y * 32;
    int tx = threadIdx.x, ty = threadIdx.y;  // 32 x 8
    #pragma unroll
    for (int i = 0; i < 32; i += 8)
        tile[ty + i][tx] = W[(size_t)(k0 + ty + i) * N + n0 + tx];
    __syncthreads();
    #pragma unroll
    for (int i = 0; i < 32; i += 8)
        Wt[(size_t)(n0 + ty + i) * K + k0 + tx] = (__bf16)tile[tx][ty + i];
}

// bqkv = concat(bq[2048], bkv[1024])
__global__ __launch_bounds__(256) void concat_bias_kernel(
    const float* __restrict__ bq, const float* __restrict__ bkv,
    float* __restrict__ bqkv) {
    int i = blockIdx.x * 256 + threadIdx.x;
    if (i < 2048) bqkv[i] = bq[i];
    else if (i < 3072) bqkv[i] = bkv[i - 2048];
}

// V cols of qkv [b*S+s][3072] (cols 2560..3071) -> Vt[(b*4+kvh)*128 + d][S]
__global__ __launch_bounds__(256) void transpose_v_kernel(
    const __bf16* __restrict__ qkv, __bf16* __restrict__ vtg, int S) {
    __shared__ __bf16 tile[32][33];
    int s0 = blockIdx.x * 32, d0 = blockIdx.y * 32, z = blockIdx.z;  // z = b*4+kvh
    int b = z >> 2, kvh = z & 3;
    int tx = threadIdx.x, ty = threadIdx.y;  // 32 x 8
    #pragma unroll
    for (int i = 0; i < 32; i += 8)
        tile[ty + i][tx] =
            qkv[((size_t)b * S + s0 + ty + i) * 3072 + 2560 + kvh * 128 + d0 + tx];
    __syncthreads();
    #pragma unroll
    for (int i = 0; i < 32; i += 8)
        vtg[((size_t)z * 128 + d0 + ty + i) * S + s0 + tx] = tile[tx][ty + i];
}

// ---------------------------------------------------------------- GEMM (m97: BK=64)
#define BM 128
#define BN 128
#define BK 64

template <typename OutT>
__global__ __launch_bounds__(256) void gemm_bt_bias_kernel(
    const __bf16* __restrict__ A, const __bf16* __restrict__ Bt,
    const float* __restrict__ bias, OutT* __restrict__ C,
    int M, int N, int K) {
    __shared__ __bf16 As[BM * BK];  // 16 KB, 128B rows, unpadded (DMA dest)
    __shared__ __bf16 Bs[BN * BK];
    int tid  = threadIdx.x;
    int bm   = blockIdx.x;
    int bn   = blockIdx.y;
    int wave = tid >> 6;
    int lane = tid & 63;
    int wm   = (wave >> 1) * 64;
    int wn   = (wave & 1) * 64;
    int quad = lane >> 4;
    int l16  = lane & 15;
    int gr   = wave * 32 + (lane >> 3);   // staging row (+i*8)
    int gc   = (lane & 7) * 8;            // staging col (bf16 elems)

    f32x4 acc[4][4];
    f32x4 zero = {0.f, 0.f, 0.f, 0.f};
    #pragma unroll
    for (int i = 0; i < 4; ++i)
        #pragma unroll
        for (int j = 0; j < 4; ++j) acc[i][j] = zero;

    const __bf16* Abase = A  + (size_t)(bm * BM) * K;
    const __bf16* Bbase = Bt + (size_t)(bn * BN) * K;

    for (int k0 = 0; k0 < K; k0 += BK) {
        if (k0) __syncthreads();
        #pragma unroll
        for (int i = 0; i < 4; ++i) {
            GLD_LDS16(Abase + (size_t)(gr + i * 8) * K + k0 + gc,
                      &As[(wave * 32 + i * 8) * BK]);
            GLD_LDS16(Bbase + (size_t)(gr + i * 8) * K + k0 + gc,
                      &Bs[(wave * 32 + i * 8) * BK]);
        }
        __syncthreads();  // drains vmcnt -> LDS data visible

        bf16x8 af[4][2], bf[4][2];
        #pragma unroll
        for (int i = 0; i < 4; ++i)
            #pragma unroll
            for (int kc = 0; kc < 2; ++kc)
                af[i][kc] = *(bf16x8*)&As[(wm + i * 16 + l16) * BK + kc * 32 + quad * 8];
        #pragma unroll
        for (int j = 0; j < 4; ++j)
            #pragma unroll
            for (int kc = 0; kc < 2; ++kc)
                bf[j][kc] = *(bf16x8*)&Bs[(wn + j * 16 + l16) * BK + kc * 32 + quad * 8];
        #pragma unroll
        for (int kc = 0; kc < 2; ++kc)
            #pragma unroll
            for (int i = 0; i < 4; ++i)
                #pragma unroll
                for (int j = 0; j < 4; ++j)
                    acc[i][j] = __builtin_amdgcn_mfma_f32_16x16x32_bf16(
                        af[i][kc], bf[j][kc], acc[i][j], 0, 0, 0);
    }

    // D layout (HW-verified m89/m91): row = quad*4+reg, col = l16
    #pragma unroll
    for (int i = 0; i < 4; ++i) {
        int row = bm * BM + wm + i * 16 + quad * 4;
        #pragma unroll
        for (int j = 0; j < 4; ++j) {
            int col  = bn * BN + wn + j * 16 + l16;
            float bv = bias[col];
            #pragma unroll
            for (int r = 0; r < 4; ++r)
                C[(size_t)(row + r) * N + col] = (OutT)(acc[i][j][r] + bv);
        }
    }
}

// ---------------------------------------------------------------- RoPE (in-place, bf16)
__global__ __launch_bounds__(256) void rope_kernel(
    __bf16* __restrict__ buf, const float* __restrict__ cosp,
    const float* __restrict__ sinp, int heads, int rowstride, int coloff,
    int S, int total) {
    int idx = blockIdx.x * 256 + threadIdx.x;
    if (idx >= total) return;
    int d  = idx & 63;
    int t2 = idx >> 6;
    int h  = t2 % heads;
    int r  = t2 / heads;
    int s  = r & (S - 1);
    size_t base = (size_t)r * rowstride + coloff + h * 128;
    float x1 = (float)buf[base + d];
    float x2 = (float)buf[base + d + 64];
    float c  = cosp[s * 64 + d];
    float sn = sinp[s * 64 + d];
    buf[base + d]      = (__bf16)(x1 * c - x2 * sn);
    buf[base + d + 64] = (__bf16)(x1 * sn + x2 * c);
}

// ---------------------------------------------------------------- MFMA flash attention
// DIAGNOSTIC ROUND: template<MODE> ablation (methodology: after 3 failed
// structural predictions, measure which subsystem owns the ~12.7k-cycle
// iteration wall). MODE 0 = real kernel (r4-identical, runs LAST, writes the
// full vobuf -> correctness preserved). Diagnostic dispatches write garbage
// into vobuf first and are fully overwritten.
//  MODE 1: V loads from fixed (L1-resident) address  -> isolates V-cache miss cost
//  MODE 2: softmax removed (P = masked scores)       -> isolates serial softmax cost
//  MODE 3: P-LDS + PV + rescale removed (asm sinks)  -> isolates PV-half cost
//  MODE 4: alt block->(b,kvh) map (contiguous chunks)-> tests XCD-affinity reality
// DCE guards per rule #17: asm volatile keep-alives on s_t and vf in MODE 3.
// Tripwires: all variants VGPR <= ~128, WRITE_SIZE ~16384 KB, no scratch.

template<int MODE>
__global__ __launch_bounds__(256) void flash_mfma_kernel(
    const __bf16* __restrict__ qkv,  // [B*S][3072]: q(0..2047)|k(2048..2559)|v
    const __bf16* __restrict__ vtg,  // [(b*4+kvh)*128 + d][S]  (V transposed)
    __bf16* __restrict__ vo,         // [B*S][2048]
    const int* __restrict__ causal_p, int S) {
    __shared__ __bf16 Ks[2][64 * 128];   // 32 KB, swizzled lane-linear
    __shared__ __bf16 Ps[4 * 16 * 64];   // 8 KB, XOR-swizzled rows

    const int QKV = 3072;
    int tid  = threadIdx.x;
    int wave = tid >> 6;
    int lane = tid & 63;
    int quad = lane >> 4;
    int l16  = lane & 15;
    int id   = blockIdx.x;
    int b, kvh, hh, qti;
    if constexpr (MODE == 4) {
        int grpi = id >> 7;          // contiguous 128-block chunks per (b,kvh)
        b = grpi >> 2; kvh = grpi & 3;
        int rest = id & 127;
        hh = rest & 3; qti = rest >> 2;
    } else {
        int xcd = id & 7;            // id%8 -> (b,kvh): XCD L2 affinity
        b = xcd >> 2; kvh = xcd & 3;
        int rest = id >> 3;
        hh = rest & 3; qti = rest >> 2;
    }
    int qt = 31 - qti;               // longest (causal) blocks dispatch first
    int h  = kvh * 4 + hh;
    int causal = causal_p[0];
    const float SCALE = 0.08838834764831845f;  // 1/sqrt(128)

    const __bf16* vB = vtg + ((size_t)(b * 4 + kvh) * 128) * S;
    char* psw = (char*)Ps + wave * 2048;   // 16 rows x 128B per wave

    int q0 = qt * 64;
    int nt = causal ? (qt + 1) : (S / 64);

    // Q A-frags: lane holds row l16 of the wave's 16-row tile
    bf16x8 a_frag[4];
    size_t qrow = ((size_t)b * S + q0 + wave * 16 + l16) * QKV + h * 128 + quad * 8;
    #pragma unroll
    for (int kc = 0; kc < 4; ++kc)
        a_frag[kc] = *(const bf16x8*)(qkv + qrow + kc * 32);

    f32x4 o_acc[8];
    f32x4 zero4 = {0.f, 0.f, 0.f, 0.f};
    #pragma unroll
    for (int dt = 0; dt < 8; ++dt) o_acc[dt] = zero4;
    float m_[4], l_[4];  // m_: row max; l_: PER-LANE partial sum
    #pragma unroll
    for (int r = 0; r < 4; ++r) { m_[r] = -1e30f; l_[r] = (MODE == 2) ? 1.f : 0.f; }
    int qrow_d = q0 + wave * 16 + quad * 4;

    // prologue: DMA K(0) -> Ks[0]; wave w stages keys w*16..w*16+15
    {
        size_t kg = ((size_t)b * S + wave * 16 + l16) * QKV + 2048 + kvh * 128 + quad * 8;
        #pragma unroll
        for (int kc = 0; kc < 4; ++kc)
            GLD_LDS16(qkv + kg + kc * 32, &Ks[0][(wave * 4 + kc) * 512]);
    }

    for (int t = 0; t < nt; ++t) {
        int cur = t & 1;
        __syncthreads();  // drains vmcnt: K(t) DMA complete; syncs buffers
        if (t + 1 < nt) {  // prefetch K(t+1) into the other buffer
            size_t kg = ((size_t)b * S + (t + 1) * 64 + wave * 16 + l16) * QKV
                        + 2048 + kvh * 128 + quad * 8;
            #pragma unroll
            for (int kc = 0; kc < 4; ++kc)
                GLD_LDS16(qkv + kg + kc * 32, &Ks[1 - cur][(wave * 4 + kc) * 512]);
        }
        int j0 = t * 64;
        int j0v = (MODE == 1) ? 0 : j0;   // MODE 1: fixed addr, L1-resident

        // V register prefetch (consumed after softmax -> latency hidden)
        bf16x8 vf[8][2];
        #pragma unroll
        for (int dt = 0; dt < 8; ++dt) {
            const __bf16* vp = vB + (size_t)(dt * 16 + l16) * S + j0v + quad * 8;
            vf[dt][0] = *(const bf16x8*)(vp);
            vf[dt][1] = *(const bf16x8*)(vp + 32);
        }

        // S = Q @ K^T  (K frags from swizzled LDS, conflict-free)
        f32x4 s_t[4];
        #pragma unroll
        for (int jt = 0; jt < 4; ++jt) s_t[jt] = zero4;
        #pragma unroll
        for (int jt = 0; jt < 4; ++jt)
            #pragma unroll
            for (int kc = 0; kc < 4; ++kc) {
                bf16x8 kf = *(bf16x8*)&Ks[cur][(jt * 4 + kc) * 512 + lane * 8];
                s_t[jt] = __builtin_amdgcn_mfma_f32_16x16x32_bf16(
                    a_frag[kc], kf, s_t[jt], 0, 0, 0);
            }

        // scale + causal mask (diagonal tile only)
        int diag = causal && (t == nt - 1);
        #pragma unroll
        for (int jt = 0; jt < 4; ++jt)
            #pragma unroll
            for (int r = 0; r < 4; ++r) {
                float sv = s_t[jt][r] * SCALE;
                if (diag && (j0 + jt * 16 + l16 > qrow_d + r)) sv = -1e30f;
                s_t[jt][r] = sv;
            }

        // online softmax: DPP max-reduce, per-lane l partials
        if constexpr (MODE != 2) {
            float alpha[4];
            #pragma unroll
            for (int r = 0; r < 4; ++r) {
                float v = fmaxf(fmaxf(s_t[0][r], s_t[1][r]),
                                fmaxf(s_t[2][r], s_t[3][r]));
                v = rowmax16(v);
                float m_new = fmaxf(m_[r], v);
                alpha[r] = __expf(m_[r] - m_new);
                m_[r] = m_new;
                float rs = 0.f;
                #pragma unroll
                for (int jt = 0; jt < 4; ++jt) {
                    float p = __expf(s_t[jt][r] - m_new);
                    s_t[jt][r] = p;
                    rs += p;
                }
                l_[r] = l_[r] * alpha[r] + rs;
            }
            if constexpr (MODE != 3) {
                #pragma unroll
                for (int dt = 0; dt < 8; ++dt)
                    #pragma unroll
                    for (int r = 0; r < 4; ++r) o_acc[dt][r] *= alpha[r];
            }
        }

        if constexpr (MODE != 3) {
            // P (C-layout) -> per-wave LDS region, XOR-swizzled (no barrier needed)
            #pragma unroll
            for (int jt = 0; jt < 4; ++jt)
                #pragma unroll
                for (int r = 0; r < 4; ++r) {
                    int prow = quad * 4 + r;
                    int inb  = (jt * 16 + l16) * 2;
                    *(__bf16*)(psw + prow * 128 + (inb ^ ((prow & 7) << 4))) =
                        (__bf16)s_t[jt][r];
                }
            // P A-frags back from LDS; PV with prefetched V frags
            int rb  = l16 * 128;
            int swz = (l16 & 7) << 4;
            bf16x8 p0 = *(bf16x8*)(psw + rb + ((quad * 16) ^ swz));
            bf16x8 p1 = *(bf16x8*)(psw + rb + ((64 + quad * 16) ^ swz));
            #pragma unroll
            for (int dt = 0; dt < 8; ++dt) {
                o_acc[dt] = __builtin_amdgcn_mfma_f32_16x16x32_bf16(
                    p0, vf[dt][0], o_acc[dt], 0, 0, 0);
                o_acc[dt] = __builtin_amdgcn_mfma_f32_16x16x32_bf16(
                    p1, vf[dt][1], o_acc[dt], 0, 0, 0);
            }
        } else {
            // keep softmax results + V loads live without P/PV (rule #17)
            #pragma unroll
            for (int jt = 0; jt < 4; ++jt)
                asm volatile("" :: "v"(s_t[jt][0]), "v"(s_t[jt][1]),
                                   "v"(s_t[jt][2]), "v"(s_t[jt][3]));
            #pragma unroll
            for (int dt = 0; dt < 8; ++dt) {
                float k0 = (float)vf[dt][0][0];
                float k1 = (float)vf[dt][1][0];
                asm volatile("" :: "v"(k0), "v"(k1));
            }
        }
    }

    // deferred l reduction (DPP) + normalize + store
    float invl[4];
    #pragma unroll
    for (int r = 0; r < 4; ++r) invl[r] = 1.f / rowsum16(l_[r]);
    size_t obase = ((size_t)b * S + q0 + wave * 16 + quad * 4) * 2048
                   + h * 128 + l16;
    #pragma unroll
    for (int dt = 0; dt < 8; ++dt)
        #pragma unroll
        for (int r = 0; r < 4; ++r)
            vo[obase + (size_t)r * 2048 + dt * 16] = (__bf16)(o_acc[dt][r] * invl[r]);
}

// ---------------------------------------------------------------- launch

extern "C" void kernel_launch(void* const* d_in, const int* in_sizes, int n_in,
                              void* d_out, int out_size, void* d_ws, size_t ws_size,
                              hipStream_t stream) {
    const float* x    = (const float*)d_in[0];
    const float* cosp = (const float*)d_in[1];
    const float* sinp = (const float*)d_in[2];
    const float* Wq   = (const float*)d_in[3];
    const float* bq   = (const float*)d_in[4];
    const float* Wkv  = (const float*)d_in[5];
    const float* bkv  = (const float*)d_in[6];
    const float* Wo   = (const float*)d_in[7];
    const float* bo   = (const float*)d_in[8];
    const int* causal = (const int*)d_in[9];
    float* out = (float*)d_out;

    const int B = 2, S = 2048;
    const int M = B * S;  // 4096

    // workspace layout (~60 MB)
    char* w = (char*)d_ws;
    __bf16* x16    = (__bf16*)w; w += (size_t)M * 2048 * 2;     // 16 MB; later = vobuf
    __bf16* Wqkvt  = (__bf16*)w; w += (size_t)3072 * 2048 * 2;  // 12 MB; later = vtg
    __bf16* Wot    = (__bf16*)w; w += (size_t)2048 * 2048 * 2;  //  8 MB
    float*  bqkv   = (float*)w;  w += (size_t)3072 * 4;         // 12 KB
    __bf16* qkvbuf = (__bf16*)w; w += (size_t)M * 3072 * 2;     // 24 MB
    __bf16* vobuf  = x16;    // alias: x16 dead after fused GEMM
    __bf16* vtg    = Wqkvt;  // alias: Wqkvt dead after fused GEMM (4 MB <= 12 MB)

    f32_to_bf16_kernel<<<(M * 2048) / (256 * 8), 256, 0, stream>>>(x, x16, (size_t)M * 2048);
    // fused weight: Wqkvt rows 0..2047 = Wq^T, rows 2048..3071 = Wkv^T
    transpose_to_bf16_kernel<<<dim3(2048 / 32, 2048 / 32), dim3(32, 8), 0, stream>>>(Wq, Wqkvt, 2048, 2048);
    transpose_to_bf16_kernel<<<dim3(1024 / 32, 2048 / 32), dim3(32, 8), 0, stream>>>(Wkv, Wqkvt + (size_t)2048 * 2048, 2048, 1024);
    transpose_to_bf16_kernel<<<dim3(2048 / 32, 2048 / 32), dim3(32, 8), 0, stream>>>(Wo, Wot, 2048, 2048);
    concat_bias_kernel<<<12, 256, 0, stream>>>(bq, bkv, bqkv);
    // fused QKV projection: [4096][3072]
    gemm_bt_bias_kernel<__bf16><<<dim3(M / BM, 3072 / BN), 256, 0, stream>>>(x16, Wqkvt, bqkv, qkvbuf, M, 3072, 2048);
    // RoPE on q (16 heads, col 0) and k (4 heads, col 2048)
    {
        int totq = M * 16 * 64;
        rope_kernel<<<(totq + 255) / 256, 256, 0, stream>>>(qkvbuf, cosp, sinp, 16, 3072, 0, S, totq);
        int totk = M * 4 * 64;
        rope_kernel<<<(totk + 255) / 256, 256, 0, stream>>>(qkvbuf, cosp, sinp, 4, 3072, 2048, S, totk);
    }
    // V -> dim-major global layout
    transpose_v_kernel<<<dim3(S / 32, 128 / 32, B * 4), dim3(32, 8), 0, stream>>>(qkvbuf, vtg, S);

    // ---- DIAGNOSTIC ablation dispatches (write garbage into vobuf; fully
    // overwritten by the real MODE 0 dispatch below) ----
    flash_mfma_kernel<1><<<dim3(1024), 256, 0, stream>>>(qkvbuf, vtg, vobuf, causal, S);
    flash_mfma_kernel<2><<<dim3(1024), 256, 0, stream>>>(qkvbuf, vtg, vobuf, causal, S);
    flash_mfma_kernel<3><<<dim3(1024), 256, 0, stream>>>(qkvbuf, vtg, vobuf, causal, S);
    flash_mfma_kernel<4><<<dim3(1024), 256, 0, stream>>>(qkvbuf, vtg, vobuf, causal, S);

    // real flash attention (MODE 0), writes the authoritative vobuf
    flash_mfma_kernel<0><<<dim3(1024), 256, 0, stream>>>(qkvbuf, vtg, vobuf, causal, S);
    // output projection (fp32 out)
    gemm_bt_bias_kernel<float><<<dim3(M / BM, 2048 / BN), 256, 0, stream>>>(vobuf, Wot, bo, out, M, 2048, 2048);
}

// Round 7
// 528.166 us; speedup vs baseline: 2.0914x; 2.0914x over previous
//
#include <hip/hip_runtime.h>
#include <hip/hip_bf16.h>

typedef __bf16 bf16x8 __attribute__((ext_vector_type(8)));
typedef float  f32x4  __attribute__((ext_vector_type(4)));
typedef unsigned int u32;

// async global->LDS, 16B/lane; LDS dest = wave-uniform base + lane*16 (m97/m104)
#define GLD_LDS16(gp, lp) __builtin_amdgcn_global_load_lds( \
    (const __attribute__((address_space(1))) u32*)(gp), \
    (__attribute__((address_space(3))) u32*)(lp), 16, 0, 0)

// DPP cyclic rotate within 16-lane rows (row_ror:N = 0x120|N) — VALU-pipe cross-lane
template<int CTRL>
__device__ __forceinline__ float dpp_rot(float x) {
    int y = __builtin_amdgcn_update_dpp(__float_as_int(x), __float_as_int(x),
                                        CTRL, 0xF, 0xF, false);
    return __int_as_float(y);
}
__device__ __forceinline__ float rowmax16(float x) {
    x = fmaxf(x, dpp_rot<0x121>(x));
    x = fmaxf(x, dpp_rot<0x122>(x));
    x = fmaxf(x, dpp_rot<0x124>(x));
    x = fmaxf(x, dpp_rot<0x128>(x));
    return x;
}
__device__ __forceinline__ float rowsum16(float x) {
    x += dpp_rot<0x121>(x);
    x += dpp_rot<0x122>(x);
    x += dpp_rot<0x124>(x);
    x += dpp_rot<0x128>(x);
    return x;
}

// ---------------------------------------------------------------- converts

__global__ __launch_bounds__(256) void f32_to_bf16_kernel(
    const float* __restrict__ in, __bf16* __restrict__ out, size_t n) {
    size_t i = ((size_t)blockIdx.x * 256 + threadIdx.x) * 8;
    if (i >= n) return;
    float4 a = *(const float4*)(in + i);
    float4 b = *(const float4*)(in + i + 4);
    bf16x8 v;
    v[0] = (__bf16)a.x; v[1] = (__bf16)a.y; v[2] = (__bf16)a.z; v[3] = (__bf16)a.w;
    v[4] = (__bf16)b.x; v[5] = (__bf16)b.y; v[6] = (__bf16)b.z; v[7] = (__bf16)b.w;
    *(bf16x8*)(out + i) = v;
}

// W[K][N] fp32  ->  Wt[N][K] bf16   (32x32 LDS tile transpose)
__global__ __launch_bounds__(256) void transpose_to_bf16_kernel(
    const float* __restrict__ W, __bf16* __restrict__ Wt, int K, int N) {
    __shared__ float tile[32][33];
    int n0 = blockIdx.x * 32, k0 = blockIdx.y * 32;
    int tx = threadIdx.x, ty = threadIdx.y;  // 32 x 8
    #pragma unroll
    for (int i = 0; i < 32; i += 8)
        tile[ty + i][tx] = W[(size_t)(k0 + ty + i) * N + n0 + tx];
    __syncthreads();
    #pragma unroll
    for (int i = 0; i < 32; i += 8)
        Wt[(size_t)(n0 + ty + i) * K + k0 + tx] = (__bf16)tile[tx][ty + i];
}

// bqkv = concat(bq[2048], bkv[1024])
__global__ __launch_bounds__(256) void concat_bias_kernel(
    const float* __restrict__ bq, const float* __restrict__ bkv,
    float* __restrict__ bqkv) {
    int i = blockIdx.x * 256 + threadIdx.x;
    if (i < 2048) bqkv[i] = bq[i];
    else if (i < 3072) bqkv[i] = bkv[i - 2048];
}

// V cols of qkv [b*S+s][3072] (cols 2560..3071) -> Vt[(b*4+kvh)*128 + d][S]
__global__ __launch_bounds__(256) void transpose_v_kernel(
    const __bf16* __restrict__ qkv, __bf16* __restrict__ vtg, int S) {
    __shared__ __bf16 tile[32][33];
    int s0 = blockIdx.x * 32, d0 = blockIdx.y * 32, z = blockIdx.z;  // z = b*4+kvh
    int b = z >> 2, kvh = z & 3;
    int tx = threadIdx.x, ty = threadIdx.y;  // 32 x 8
    #pragma unroll
    for (int i = 0; i < 32; i += 8)
        tile[ty + i][tx] =
            qkv[((size_t)b * S + s0 + ty + i) * 3072 + 2560 + kvh * 128 + d0 + tx];
    __syncthreads();
    #pragma unroll
    for (int i = 0; i < 32; i += 8)
        vtg[((size_t)z * 128 + d0 + ty + i) * S + s0 + tx] = tile[tx][ty + i];
}

// ---------------------------------------------------------------- GEMM (m97: BK=64)
#define BM 128
#define BN 128
#define BK 64

template <typename OutT>
__global__ __launch_bounds__(256) void gemm_bt_bias_kernel(
    const __bf16* __restrict__ A, const __bf16* __restrict__ Bt,
    const float* __restrict__ bias, OutT* __restrict__ C,
    int M, int N, int K) {
    __shared__ __bf16 As[BM * BK];  // 16 KB, 128B rows, unpadded (DMA dest)
    __shared__ __bf16 Bs[BN * BK];
    int tid  = threadIdx.x;
    int bm   = blockIdx.x;
    int bn   = blockIdx.y;
    int wave = tid >> 6;
    int lane = tid & 63;
    int wm   = (wave >> 1) * 64;
    int wn   = (wave & 1) * 64;
    int quad = lane >> 4;
    int l16  = lane & 15;
    int gr   = wave * 32 + (lane >> 3);   // staging row (+i*8)
    int gc   = (lane & 7) * 8;            // staging col (bf16 elems)

    f32x4 acc[4][4];
    f32x4 zero = {0.f, 0.f, 0.f, 0.f};
    #pragma unroll
    for (int i = 0; i < 4; ++i)
        #pragma unroll
        for (int j = 0; j < 4; ++j) acc[i][j] = zero;

    const __bf16* Abase = A  + (size_t)(bm * BM) * K;
    const __bf16* Bbase = Bt + (size_t)(bn * BN) * K;

    for (int k0 = 0; k0 < K; k0 += BK) {
        if (k0) __syncthreads();
        #pragma unroll
        for (int i = 0; i < 4; ++i) {
            GLD_LDS16(Abase + (size_t)(gr + i * 8) * K + k0 + gc,
                      &As[(wave * 32 + i * 8) * BK]);
            GLD_LDS16(Bbase + (size_t)(gr + i * 8) * K + k0 + gc,
                      &Bs[(wave * 32 + i * 8) * BK]);
        }
        __syncthreads();  // drains vmcnt -> LDS data visible

        bf16x8 af[4][2], bf[4][2];
        #pragma unroll
        for (int i = 0; i < 4; ++i)
            #pragma unroll
            for (int kc = 0; kc < 2; ++kc)
                af[i][kc] = *(bf16x8*)&As[(wm + i * 16 + l16) * BK + kc * 32 + quad * 8];
        #pragma unroll
        for (int j = 0; j < 4; ++j)
            #pragma unroll
            for (int kc = 0; kc < 2; ++kc)
                bf[j][kc] = *(bf16x8*)&Bs[(wn + j * 16 + l16) * BK + kc * 32 + quad * 8];
        #pragma unroll
        for (int kc = 0; kc < 2; ++kc)
            #pragma unroll
            for (int i = 0; i < 4; ++i)
                #pragma unroll
                for (int j = 0; j < 4; ++j)
                    acc[i][j] = __builtin_amdgcn_mfma_f32_16x16x32_bf16(
                        af[i][kc], bf[j][kc], acc[i][j], 0, 0, 0);
    }

    // D layout (HW-verified m89/m91): row = quad*4+reg, col = l16
    #pragma unroll
    for (int i = 0; i < 4; ++i) {
        int row = bm * BM + wm + i * 16 + quad * 4;
        #pragma unroll
        for (int j = 0; j < 4; ++j) {
            int col  = bn * BN + wn + j * 16 + l16;
            float bv = bias[col];
            #pragma unroll
            for (int r = 0; r < 4; ++r)
                C[(size_t)(row + r) * N + col] = (OutT)(acc[i][j][r] + bv);
        }
    }
}

// ---------------------------------------------------------------- RoPE (in-place, bf16)
__global__ __launch_bounds__(256) void rope_kernel(
    __bf16* __restrict__ buf, const float* __restrict__ cosp,
    const float* __restrict__ sinp, int heads, int rowstride, int coloff,
    int S, int total) {
    int idx = blockIdx.x * 256 + threadIdx.x;
    if (idx >= total) return;
    int d  = idx & 63;
    int t2 = idx >> 6;
    int h  = t2 % heads;
    int r  = t2 / heads;
    int s  = r & (S - 1);
    size_t base = (size_t)r * rowstride + coloff + h * 128;
    float x1 = (float)buf[base + d];
    float x2 = (float)buf[base + d + 64];
    float c  = cosp[s * 64 + d];
    float sn = sinp[s * 64 + d];
    buf[base + d]      = (__bf16)(x1 * c - x2 * sn);
    buf[base + d + 64] = (__bf16)(x1 * sn + x2 * c);
}

// ---------------------------------------------------------------- MFMA flash attention
// KVBLK=128 on the round-0 paired structure (best measured: 164.6 us).
// Round-6 ablation: per-iteration cost is an ADDITIVE SERIAL CHAIN — core
// (barrier+K-DMA+QK) ~60us, V-latency ~38, softmax ~38, P/PV ~38; and MODE4
// proved the id%8 XCD map saves ~75us (FETCH 12->40MB without it). So the
// lever is amortization: 128-wide KV tiles halve walls/block (33 -> 17,
// pairs qt & 31-qt still sum uniformly: floor(qt/2)+floor((31-qt)/2)+2 = 17),
// halving every per-wall fixed cost, and give V loads 2x the MFMA work
// (64/iter) to hide under. QK: 8 indep 4-deep chains; PV: 8 indep 4-deep.
// For even qt the last tile's upper 64 cols are fully masked (j > qrow
// covers it) — ~3% wasted MFMA, accepted for uniformity.
// LDS: Ks 2x32KB + Ps 16KB = 80KB exactly -> 2 blocks/CU, grid 512 = exact
// residency. T5 setprio around both MFMA clusters (2 blocks/CU -> role
// diversity across blocks).
// REGISTER DISCIPLINE (r1/r2): NO min-waves launch_bounds (64-VGPR step ->
// 300MB scratch). vf[8][4]=64 VGPR full-tile V prefetch; est ~140-155 arch.
// Tripwires: WRITE_SIZE 16384 KB (spill!), LDS 81920, FETCH ~12MB.
// Fallback if spilling: sequential-half V (vf[8][2], reload between halves).

__global__ __launch_bounds__(256) void flash_mfma_kernel(
    const __bf16* __restrict__ qkv,  // [B*S][3072]: q(0..2047)|k(2048..2559)|v
    const __bf16* __restrict__ vtg,  // [(b*4+kvh)*128 + d][S]  (V transposed)
    __bf16* __restrict__ vo,         // [B*S][2048]
    const int* __restrict__ causal_p, int S) {
    __shared__ __bf16 Ks[2][128 * 128];  // 2 x 32 KB, swizzled lane-linear
    __shared__ __bf16 Ps[4 * 16 * 128];  // 16 KB, XOR-swizzled 256B rows

    const int QKV = 3072;
    int tid  = threadIdx.x;
    int wave = tid >> 6;
    int lane = tid & 63;
    int quad = lane >> 4;
    int l16  = lane & 15;
    int id   = blockIdx.x;
    int xcd  = id & 7;        // id%8 -> (b,kvh): XCD L2 affinity (MODE4-verified)
    int b    = xcd >> 2;
    int kvh  = xcd & 3;
    int rest = id >> 3;       // 0..63
    int hh   = rest & 3;
    int pair = rest >> 2;     // 0..15
    int h    = kvh * 4 + hh;
    int causal = causal_p[0];
    const float SCALE = 0.08838834764831845f;  // 1/sqrt(128)

    const __bf16* vB = vtg + ((size_t)(b * 4 + kvh) * 128) * S;
    char* psw = (char*)Ps + wave * 4096;   // 16 rows x 256B per wave

    #pragma unroll 1
    for (int phase = 0; phase < 2; ++phase) {
        int qt = phase ? (31 - pair) : pair;
        int q0 = qt * 64;
        int nt64 = causal ? (qt + 1) : (S / 64);
        int nt   = (nt64 + 1) >> 1;   // 128-col KV tiles

        // Q A-frags: lane holds row l16 of the wave's 16-row tile
        bf16x8 a_frag[4];
        size_t qrow = ((size_t)b * S + q0 + wave * 16 + l16) * QKV + h * 128 + quad * 8;
        #pragma unroll
        for (int kc = 0; kc < 4; ++kc)
            a_frag[kc] = *(const bf16x8*)(qkv + qrow + kc * 32);

        f32x4 o_acc[8];
        f32x4 zero4 = {0.f, 0.f, 0.f, 0.f};
        #pragma unroll
        for (int dt = 0; dt < 8; ++dt) o_acc[dt] = zero4;
        float m_[4], l_[4];  // m_: row max; l_: PER-LANE partial sum
        #pragma unroll
        for (int r = 0; r < 4; ++r) { m_[r] = -1e30f; l_[r] = 0.f; }
        int qrow_d = q0 + wave * 16 + quad * 4;

        __syncthreads();  // prev phase's readers done with Ks
        // prologue: DMA K tile 0. Wave w stages rows {w*16.., 64+w*16..}
        // into chunks ((w+hf*4)*4+kc) — read side jt = w+hf*4 matches.
        {
            size_t kg = ((size_t)b * S + wave * 16 + l16) * QKV + 2048 + kvh * 128 + quad * 8;
            #pragma unroll
            for (int hf = 0; hf < 2; ++hf)
                #pragma unroll
                for (int kc = 0; kc < 4; ++kc)
                    GLD_LDS16(qkv + kg + (size_t)hf * 64 * QKV + kc * 32,
                              &Ks[0][((wave + hf * 4) * 4 + kc) * 512]);
        }

        #pragma unroll 1
        for (int t = 0; t < nt; ++t) {
            int cur = t & 1;
            __syncthreads();  // drains vmcnt: K(t) DMA complete; syncs buffers
            if (t + 1 < nt) {  // prefetch K(t+1) into the other buffer
                size_t kg = ((size_t)b * S + (t + 1) * 128 + wave * 16 + l16) * QKV
                            + 2048 + kvh * 128 + quad * 8;
                #pragma unroll
                for (int hf = 0; hf < 2; ++hf)
                    #pragma unroll
                    for (int kc = 0; kc < 4; ++kc)
                        GLD_LDS16(qkv + kg + (size_t)hf * 64 * QKV + kc * 32,
                                  &Ks[1 - cur][((wave + hf * 4) * 4 + kc) * 512]);
            }
            int j0 = t * 128;

            // V full-tile register prefetch (consumed after softmax)
            bf16x8 vf[8][4];
            #pragma unroll
            for (int dt = 0; dt < 8; ++dt) {
                const __bf16* vp = vB + (size_t)(dt * 16 + l16) * S + j0 + quad * 8;
                #pragma unroll
                for (int ks = 0; ks < 4; ++ks)
                    vf[dt][ks] = *(const bf16x8*)(vp + ks * 32);
            }

            // S = Q @ K^T : 8 independent 4-deep MFMA chains
            f32x4 s_t[8];
            #pragma unroll
            for (int jt = 0; jt < 8; ++jt) s_t[jt] = zero4;
            __builtin_amdgcn_s_setprio(1);
            #pragma unroll
            for (int jt = 0; jt < 8; ++jt)
                #pragma unroll
                for (int kc = 0; kc < 4; ++kc) {
                    bf16x8 kf = *(bf16x8*)&Ks[cur][(jt * 4 + kc) * 512 + lane * 8];
                    s_t[jt] = __builtin_amdgcn_mfma_f32_16x16x32_bf16(
                        a_frag[kc], kf, s_t[jt], 0, 0, 0);
                }
            __builtin_amdgcn_s_setprio(0);

            // scale + causal mask (diagonal tile only; j>qrow also kills the
            // dead upper half of the last tile for even qt)
            int diag = causal && (t == nt - 1);
            #pragma unroll
            for (int jt = 0; jt < 8; ++jt)
                #pragma unroll
                for (int r = 0; r < 4; ++r) {
                    float sv = s_t[jt][r] * SCALE;
                    if (diag && (j0 + jt * 16 + l16 > qrow_d + r)) sv = -1e30f;
                    s_t[jt][r] = sv;
                }

            // online softmax: DPP max-reduce, per-lane l partials
            float alpha[4];
            #pragma unroll
            for (int r = 0; r < 4; ++r) {
                float v01 = fmaxf(s_t[0][r], s_t[1][r]);
                float v23 = fmaxf(s_t[2][r], s_t[3][r]);
                float v45 = fmaxf(s_t[4][r], s_t[5][r]);
                float v67 = fmaxf(s_t[6][r], s_t[7][r]);
                float v = fmaxf(fmaxf(v01, v23), fmaxf(v45, v67));
                v = rowmax16(v);
                float m_new = fmaxf(m_[r], v);
                alpha[r] = __expf(m_[r] - m_new);
                m_[r] = m_new;
                float rs = 0.f;
                #pragma unroll
                for (int jt = 0; jt < 8; ++jt) {
                    float p = __expf(s_t[jt][r] - m_new);
                    s_t[jt][r] = p;
                    rs += p;
                }
                l_[r] = l_[r] * alpha[r] + rs;
            }
            // P (C-layout) -> per-wave LDS region, XOR-swizzled (no barrier)
            #pragma unroll
            for (int jt = 0; jt < 8; ++jt)
                #pragma unroll
                for (int r = 0; r < 4; ++r) {
                    int prow = quad * 4 + r;
                    int inb  = (jt * 16 + l16) * 2;
                    *(__bf16*)(psw + prow * 256 + (inb ^ ((prow & 7) << 4))) =
                        (__bf16)s_t[jt][r];
                }
            #pragma unroll
            for (int dt = 0; dt < 8; ++dt)
                #pragma unroll
                for (int r = 0; r < 4; ++r) o_acc[dt][r] *= alpha[r];

            // P A-frags back from LDS; PV: 8 independent 4-deep chains
            int rb  = l16 * 256;
            int swz = (l16 & 7) << 4;
            bf16x8 pa[4];
            #pragma unroll
            for (int ks = 0; ks < 4; ++ks)
                pa[ks] = *(bf16x8*)(psw + rb + ((ks * 64 + quad * 16) ^ swz));
            __builtin_amdgcn_s_setprio(1);
            #pragma unroll
            for (int dt = 0; dt < 8; ++dt)
                #pragma unroll
                for (int ks = 0; ks < 4; ++ks)
                    o_acc[dt] = __builtin_amdgcn_mfma_f32_16x16x32_bf16(
                        pa[ks], vf[dt][ks], o_acc[dt], 0, 0, 0);
            __builtin_amdgcn_s_setprio(0);
        }

        // deferred l reduction (DPP) + normalize + store
        float invl[4];
        #pragma unroll
        for (int r = 0; r < 4; ++r) invl[r] = 1.f / rowsum16(l_[r]);
        size_t obase = ((size_t)b * S + q0 + wave * 16 + quad * 4) * 2048
                       + h * 128 + l16;
        #pragma unroll
        for (int dt = 0; dt < 8; ++dt)
            #pragma unroll
            for (int r = 0; r < 4; ++r)
                vo[obase + (size_t)r * 2048 + dt * 16] = (__bf16)(o_acc[dt][r] * invl[r]);
    }
}

// ---------------------------------------------------------------- launch

extern "C" void kernel_launch(void* const* d_in, const int* in_sizes, int n_in,
                              void* d_out, int out_size, void* d_ws, size_t ws_size,
                              hipStream_t stream) {
    const float* x    = (const float*)d_in[0];
    const float* cosp = (const float*)d_in[1];
    const float* sinp = (const float*)d_in[2];
    const float* Wq   = (const float*)d_in[3];
    const float* bq   = (const float*)d_in[4];
    const float* Wkv  = (const float*)d_in[5];
    const float* bkv  = (const float*)d_in[6];
    const float* Wo   = (const float*)d_in[7];
    const float* bo   = (const float*)d_in[8];
    const int* causal = (const int*)d_in[9];
    float* out = (float*)d_out;

    const int B = 2, S = 2048;
    const int M = B * S;  // 4096

    // workspace layout (~60 MB)
    char* w = (char*)d_ws;
    __bf16* x16    = (__bf16*)w; w += (size_t)M * 2048 * 2;     // 16 MB; later = vobuf
    __bf16* Wqkvt  = (__bf16*)w; w += (size_t)3072 * 2048 * 2;  // 12 MB; later = vtg
    __bf16* Wot    = (__bf16*)w; w += (size_t)2048 * 2048 * 2;  //  8 MB
    float*  bqkv   = (float*)w;  w += (size_t)3072 * 4;         // 12 KB
    __bf16* qkvbuf = (__bf16*)w; w += (size_t)M * 3072 * 2;     // 24 MB
    __bf16* vobuf  = x16;    // alias: x16 dead after fused GEMM
    __bf16* vtg    = Wqkvt;  // alias: Wqkvt dead after fused GEMM (4 MB <= 12 MB)

    f32_to_bf16_kernel<<<(M * 2048) / (256 * 8), 256, 0, stream>>>(x, x16, (size_t)M * 2048);
    // fused weight: Wqkvt rows 0..2047 = Wq^T, rows 2048..3071 = Wkv^T
    transpose_to_bf16_kernel<<<dim3(2048 / 32, 2048 / 32), dim3(32, 8), 0, stream>>>(Wq, Wqkvt, 2048, 2048);
    transpose_to_bf16_kernel<<<dim3(1024 / 32, 2048 / 32), dim3(32, 8), 0, stream>>>(Wkv, Wqkvt + (size_t)2048 * 2048, 2048, 1024);
    transpose_to_bf16_kernel<<<dim3(2048 / 32, 2048 / 32), dim3(32, 8), 0, stream>>>(Wo, Wot, 2048, 2048);
    concat_bias_kernel<<<12, 256, 0, stream>>>(bq, bkv, bqkv);
    // fused QKV projection: [4096][3072]
    gemm_bt_bias_kernel<__bf16><<<dim3(M / BM, 3072 / BN), 256, 0, stream>>>(x16, Wqkvt, bqkv, qkvbuf, M, 3072, 2048);
    // RoPE on q (16 heads, col 0) and k (4 heads, col 2048)
    {
        int totq = M * 16 * 64;
        rope_kernel<<<(totq + 255) / 256, 256, 0, stream>>>(qkvbuf, cosp, sinp, 16, 3072, 0, S, totq);
        int totk = M * 4 * 64;
        rope_kernel<<<(totk + 255) / 256, 256, 0, stream>>>(qkvbuf, cosp, sinp, 4, 3072, 2048, S, totk);
    }
    // V -> dim-major global layout
    transpose_v_kernel<<<dim3(S / 32, 128 / 32, B * 4), dim3(32, 8), 0, stream>>>(qkvbuf, vtg, S);
    // 512 blocks: id%8 -> (b,kvh); paired Q-tiles -> uniform 17 walls/block
    flash_mfma_kernel<<<dim3(512), 256, 0, stream>>>(qkvbuf, vtg, vobuf, causal, S);
    // output projection (fp32 out)
    gemm_bt_bias_kernel<float><<<dim3(M / BM, 2048 / BN), 256, 0, stream>>>(vobuf, Wot, bo, out, M, 2048, 2048);
}

// Round 9
// 393.157 us; speedup vs baseline: 2.8096x; 1.3434x over previous
//
#include <hip/hip_runtime.h>
#include <hip/hip_bf16.h>

typedef __bf16 bf16x8 __attribute__((ext_vector_type(8)));
typedef float  f32x4  __attribute__((ext_vector_type(4)));
typedef unsigned int u32;

// async global->LDS, 16B/lane; LDS dest = wave-uniform base + lane*16 (m97/m104)
// global SOURCE is per-lane (guide m173) — used for both K and V staging.
#define GLD_LDS16(gp, lp) __builtin_amdgcn_global_load_lds( \
    (const __attribute__((address_space(1))) u32*)(gp), \
    (__attribute__((address_space(3))) u32*)(lp), 16, 0, 0)

// DPP cyclic rotate within 16-lane rows (row_ror:N = 0x120|N) — VALU-pipe cross-lane
template<int CTRL>
__device__ __forceinline__ float dpp_rot(float x) {
    int y = __builtin_amdgcn_update_dpp(__float_as_int(x), __float_as_int(x),
                                        CTRL, 0xF, 0xF, false);
    return __int_as_float(y);
}
__device__ __forceinline__ float rowmax16(float x) {
    x = fmaxf(x, dpp_rot<0x121>(x));
    x = fmaxf(x, dpp_rot<0x122>(x));
    x = fmaxf(x, dpp_rot<0x124>(x));
    x = fmaxf(x, dpp_rot<0x128>(x));
    return x;
}
__device__ __forceinline__ float rowsum16(float x) {
    x += dpp_rot<0x121>(x);
    x += dpp_rot<0x122>(x);
    x += dpp_rot<0x124>(x);
    x += dpp_rot<0x128>(x);
    return x;
}

// ---------------------------------------------------------------- converts

__global__ __launch_bounds__(256) void f32_to_bf16_kernel(
    const float* __restrict__ in, __bf16* __restrict__ out, size_t n) {
    size_t i = ((size_t)blockIdx.x * 256 + threadIdx.x) * 8;
    if (i >= n) return;
    float4 a = *(const float4*)(in + i);
    float4 b = *(const float4*)(in + i + 4);
    bf16x8 v;
    v[0] = (__bf16)a.x; v[1] = (__bf16)a.y; v[2] = (__bf16)a.z; v[3] = (__bf16)a.w;
    v[4] = (__bf16)b.x; v[5] = (__bf16)b.y; v[6] = (__bf16)b.z; v[7] = (__bf16)b.w;
    *(bf16x8*)(out + i) = v;
}

// W[K][N] fp32  ->  Wt[N][K] bf16   (32x32 LDS tile transpose)
__global__ __launch_bounds__(256) void transpose_to_bf16_kernel(
    const float* __restrict__ W, __bf16* __restrict__ Wt, int K, int N) {
    __shared__ float tile[32][33];
    int n0 = blockIdx.x * 32, k0 = blockIdx.y * 32;
    int tx = threadIdx.x, ty = threadIdx.y;  // 32 x 8
    #pragma unroll
    for (int i = 0; i < 32; i += 8)
        tile[ty + i][tx] = W[(size_t)(k0 + ty + i) * N + n0 + tx];
    __syncthreads();
    #pragma unroll
    for (int i = 0; i < 32; i += 8)
        Wt[(size_t)(n0 + ty + i) * K + k0 + tx] = (__bf16)tile[tx][ty + i];
}

// bqkv = concat(bq[2048], bkv[1024])
__global__ __launch_bounds__(256) void concat_bias_kernel(
    const float* __restrict__ bq, const float* __restrict__ bkv,
    float* __restrict__ bqkv) {
    int i = blockIdx.x * 256 + threadIdx.x;
    if (i < 2048) bqkv[i] = bq[i];
    else if (i < 3072) bqkv[i] = bkv[i - 2048];
}

// V cols of qkv [b*S+s][3072] (cols 2560..3071) -> Vt[(b*4+kvh)*128 + d][S]
__global__ __launch_bounds__(256) void transpose_v_kernel(
    const __bf16* __restrict__ qkv, __bf16* __restrict__ vtg, int S) {
    __shared__ __bf16 tile[32][33];
    int s0 = blockIdx.x * 32, d0 = blockIdx.y * 32, z = blockIdx.z;  // z = b*4+kvh
    int b = z >> 2, kvh = z & 3;
    int tx = threadIdx.x, ty = threadIdx.y;  // 32 x 8
    #pragma unroll
    for (int i = 0; i < 32; i += 8)
        tile[ty + i][tx] =
            qkv[((size_t)b * S + s0 + ty + i) * 3072 + 2560 + kvh * 128 + d0 + tx];
    __syncthreads();
    #pragma unroll
    for (int i = 0; i < 32; i += 8)
        vtg[((size_t)z * 128 + d0 + ty + i) * S + s0 + tx] = tile[tx][ty + i];
}

// ---------------------------------------------------------------- GEMM (m97: BK=64)
// 1D grid + bijective XCD swizzle (T1; nwg%8==0 for both GEMMs here).
#define BM 128
#define BN 128
#define BK 64

template <typename OutT>
__global__ __launch_bounds__(256) void gemm_bt_bias_kernel(
    const __bf16* __restrict__ A, const __bf16* __restrict__ Bt,
    const float* __restrict__ bias, OutT* __restrict__ C,
    int M, int N, int K) {
    __shared__ __bf16 As[BM * BK];  // 16 KB, 128B rows, unpadded (DMA dest)
    __shared__ __bf16 Bs[BN * BK];
    int tid  = threadIdx.x;
    // XCD swizzle: contiguous chunk per XCD; within chunk bm-major (B-panel reuse)
    int nwg  = gridDim.x;
    int cpx  = nwg >> 3;
    int swzb = (blockIdx.x & 7) * cpx + (blockIdx.x >> 3);
    int nbm  = M / BM;
    int bm   = swzb % nbm;
    int bn   = swzb / nbm;
    int wave = tid >> 6;
    int lane = tid & 63;
    int wm   = (wave >> 1) * 64;
    int wn   = (wave & 1) * 64;
    int quad = lane >> 4;
    int l16  = lane & 15;
    int gr   = wave * 32 + (lane >> 3);   // staging row (+i*8)
    int gc   = (lane & 7) * 8;            // staging col (bf16 elems)

    f32x4 acc[4][4];
    f32x4 zero = {0.f, 0.f, 0.f, 0.f};
    #pragma unroll
    for (int i = 0; i < 4; ++i)
        #pragma unroll
        for (int j = 0; j < 4; ++j) acc[i][j] = zero;

    const __bf16* Abase = A  + (size_t)(bm * BM) * K;
    const __bf16* Bbase = Bt + (size_t)(bn * BN) * K;

    for (int k0 = 0; k0 < K; k0 += BK) {
        if (k0) __syncthreads();
        #pragma unroll
        for (int i = 0; i < 4; ++i) {
            GLD_LDS16(Abase + (size_t)(gr + i * 8) * K + k0 + gc,
                      &As[(wave * 32 + i * 8) * BK]);
            GLD_LDS16(Bbase + (size_t)(gr + i * 8) * K + k0 + gc,
                      &Bs[(wave * 32 + i * 8) * BK]);
        }
        __syncthreads();  // drains vmcnt -> LDS data visible

        bf16x8 af[4][2], bf[4][2];
        #pragma unroll
        for (int i = 0; i < 4; ++i)
            #pragma unroll
            for (int kc = 0; kc < 2; ++kc)
                af[i][kc] = *(bf16x8*)&As[(wm + i * 16 + l16) * BK + kc * 32 + quad * 8];
        #pragma unroll
        for (int j = 0; j < 4; ++j)
            #pragma unroll
            for (int kc = 0; kc < 2; ++kc)
                bf[j][kc] = *(bf16x8*)&Bs[(wn + j * 16 + l16) * BK + kc * 32 + quad * 8];
        #pragma unroll
        for (int kc = 0; kc < 2; ++kc)
            #pragma unroll
            for (int i = 0; i < 4; ++i)
                #pragma unroll
                for (int j = 0; j < 4; ++j)
                    acc[i][j] = __builtin_amdgcn_mfma_f32_16x16x32_bf16(
                        af[i][kc], bf[j][kc], acc[i][j], 0, 0, 0);
    }

    // D layout (HW-verified m89/m91): row = quad*4+reg, col = l16
    #pragma unroll
    for (int i = 0; i < 4; ++i) {
        int row = bm * BM + wm + i * 16 + quad * 4;
        #pragma unroll
        for (int j = 0; j < 4; ++j) {
            int col  = bn * BN + wn + j * 16 + l16;
            float bv = bias[col];
            #pragma unroll
            for (int r = 0; r < 4; ++r)
                C[(size_t)(row + r) * N + col] = (OutT)(acc[i][j][r] + bv);
        }
    }
}

// ---------------------------------------------------------------- RoPE (in-place, bf16)
__global__ __launch_bounds__(256) void rope_kernel(
    __bf16* __restrict__ buf, const float* __restrict__ cosp,
    const float* __restrict__ sinp, int heads, int rowstride, int coloff,
    int S, int total) {
    int idx = blockIdx.x * 256 + threadIdx.x;
    if (idx >= total) return;
    int d  = idx & 63;
    int t2 = idx >> 6;
    int h  = t2 % heads;
    int r  = t2 / heads;
    int s  = r & (S - 1);
    size_t base = (size_t)r * rowstride + coloff + h * 128;
    float x1 = (float)buf[base + d];
    float x2 = (float)buf[base + d + 64];
    float c  = cosp[s * 64 + d];
    float sn = sinp[s * 64 + d];
    buf[base + d]      = (__bf16)(x1 * c - x2 * sn);
    buf[base + d + 64] = (__bf16)(x1 * sn + x2 * c);
}

// ---------------------------------------------------------------- MFMA flash attention
// r0 paired structure (proven 164.6us) + V STAGED THROUGH LDS via
// global_load_lds (round-8 change; round-9 = identical resubmit after infra
// failure — kernel audited: uniform barriers, in-bounds DMA, lane-consistent
// writer/reader mapping, bijective GEMM swizzle, graph-capture safe).
// Rationale (r6 ablation + r7 failure): registers pin occupancy at 2
// waves/SIMD; vf[8][2] was 64 VGPR of staging buffer AND 4x redundant V L2
// traffic (each wave loaded the whole 16KB V tile); MODE1 priced the exposed
// V latency at ~38us. Vs is DMA'd (zero VGPR) double-buffered alongside K —
// V arrives a full wall early through the same prefetch pipeline; PV reads
// B-frags from LDS at consumption. DMA lane-consistency: source addr uses
// only (l16,quad,dt,kc,j0) — not wave — and reader lane reads its own lane
// slot, so writer wave identity is irrelevant (same argument as Ks).
// LDS 72KB -> 2 blocks/CU.
// REGISTER DISCIPLINE (r1/r2/r7): NO min-waves launch_bounds; no new
// per-wave arrays. Tripwires: VGPR_Count ~64-88 (should DROP vs r0's 88),
// WRITE_SIZE 16384 KB, LDS 73728, bank conflicts ~0.

__global__ __launch_bounds__(256) void flash_mfma_kernel(
    const __bf16* __restrict__ qkv,  // [B*S][3072]: q(0..2047)|k(2048..2559)|v
    const __bf16* __restrict__ vtg,  // [(b*4+kvh)*128 + d][S]  (V transposed)
    __bf16* __restrict__ vo,         // [B*S][2048]
    const int* __restrict__ causal_p, int S) {
    __shared__ __bf16 Ks[2][64 * 128];   // 2 x 16 KB, lane-linear chunks
    __shared__ __bf16 Vs[2][64 * 128];   // 2 x 16 KB, lane-linear chunks
    __shared__ __bf16 Ps[4 * 16 * 64];   // 8 KB, XOR-swizzled rows (r4-proven)

    const int QKV = 3072;
    int tid  = threadIdx.x;
    int wave = tid >> 6;
    int lane = tid & 63;
    int quad = lane >> 4;
    int l16  = lane & 15;
    int id   = blockIdx.x;
    int xcd  = id & 7;           // id%8 -> (b,kvh): XCD L2 affinity (MODE4-verified)
    int b    = xcd >> 2;
    int kvh  = xcd & 3;
    int rest = id >> 3;          // 0..63
    int hh   = rest & 3;
    int pair = rest >> 2;        // 0..15
    int h    = kvh * 4 + hh;
    int causal = causal_p[0];
    const float SCALE = 0.08838834764831845f;  // 1/sqrt(128)

    const __bf16* vB = vtg + ((size_t)(b * 4 + kvh) * 128) * S;
    char* psw = (char*)Ps + wave * 2048;   // 16 rows x 128B per wave

    #pragma unroll 1
    for (int phase = 0; phase < 2; ++phase) {
        int qt = phase ? (31 - pair) : pair;
        int q0 = qt * 64;
        int nt = causal ? (qt + 1) : (S / 64);

        // Q A-frags: lane holds row l16 of the wave's 16-row tile
        bf16x8 a_frag[4];
        size_t qrow = ((size_t)b * S + q0 + wave * 16 + l16) * QKV + h * 128 + quad * 8;
        #pragma unroll
        for (int kc = 0; kc < 4; ++kc)
            a_frag[kc] = *(const bf16x8*)(qkv + qrow + kc * 32);

        f32x4 o_acc[8];
        f32x4 zero4 = {0.f, 0.f, 0.f, 0.f};
        #pragma unroll
        for (int dt = 0; dt < 8; ++dt) o_acc[dt] = zero4;
        float m_[4], l_[4];  // m_: row max; l_: PER-LANE partial sum
        #pragma unroll
        for (int r = 0; r < 4; ++r) { m_[r] = -1e30f; l_[r] = 0.f; }
        int qrow_d = q0 + wave * 16 + quad * 4;

        __syncthreads();  // protect Ks/Vs from previous phase's readers
        // prologue: DMA K(0) -> Ks[0] and V(0) -> Vs[0]
        {
            size_t kg = ((size_t)b * S + wave * 16 + l16) * QKV + 2048 + kvh * 128 + quad * 8;
            #pragma unroll
            for (int kc = 0; kc < 4; ++kc)
                GLD_LDS16(qkv + kg + kc * 32, &Ks[0][(wave * 4 + kc) * 512]);
            #pragma unroll
            for (int i = 0; i < 4; ++i) {
                int c  = wave * 4 + i;       // chunk: dt = c>>1, kc = c&1
                int dt = c >> 1, kc = c & 1;
                GLD_LDS16(vB + (size_t)(dt * 16 + l16) * S + kc * 32 + quad * 8,
                          &Vs[0][c * 512]);
            }
        }

        for (int t = 0; t < nt; ++t) {
            int cur = t & 1;
            __syncthreads();  // drains vmcnt: K(t)+V(t) DMA complete; syncs buffers
            if (t + 1 < nt) {  // prefetch K(t+1), V(t+1) into the other buffers
                size_t kg = ((size_t)b * S + (t + 1) * 64 + wave * 16 + l16) * QKV
                            + 2048 + kvh * 128 + quad * 8;
                #pragma unroll
                for (int kc = 0; kc < 4; ++kc)
                    GLD_LDS16(qkv + kg + kc * 32, &Ks[1 - cur][(wave * 4 + kc) * 512]);
                size_t vgoff = (size_t)(t + 1) * 64;
                #pragma unroll
                for (int i = 0; i < 4; ++i) {
                    int c  = wave * 4 + i;
                    int dt = c >> 1, kc = c & 1;
                    GLD_LDS16(vB + (size_t)(dt * 16 + l16) * S + vgoff + kc * 32 + quad * 8,
                              &Vs[1 - cur][c * 512]);
                }
            }
            int j0 = t * 64;

            // S = Q @ K^T  (K frags from LDS, conflict-free)
            f32x4 s_t[4];
            #pragma unroll
            for (int jt = 0; jt < 4; ++jt) s_t[jt] = zero4;
            #pragma unroll
            for (int jt = 0; jt < 4; ++jt)
                #pragma unroll
                for (int kc = 0; kc < 4; ++kc) {
                    bf16x8 kf = *(bf16x8*)&Ks[cur][(jt * 4 + kc) * 512 + lane * 8];
                    s_t[jt] = __builtin_amdgcn_mfma_f32_16x16x32_bf16(
                        a_frag[kc], kf, s_t[jt], 0, 0, 0);
                }

            // scale + causal mask (diagonal tile only)
            int diag = causal && (t == nt - 1);
            #pragma unroll
            for (int jt = 0; jt < 4; ++jt)
                #pragma unroll
                for (int r = 0; r < 4; ++r) {
                    float sv = s_t[jt][r] * SCALE;
                    if (diag && (j0 + jt * 16 + l16 > qrow_d + r)) sv = -1e30f;
                    s_t[jt][r] = sv;
                }

            // online softmax: DPP max-reduce, per-lane l partials
            float alpha[4];
            #pragma unroll
            for (int r = 0; r < 4; ++r) {
                float v = fmaxf(fmaxf(s_t[0][r], s_t[1][r]),
                                fmaxf(s_t[2][r], s_t[3][r]));
                v = rowmax16(v);
                float m_new = fmaxf(m_[r], v);
                alpha[r] = __expf(m_[r] - m_new);
                m_[r] = m_new;
                float rs = 0.f;
                #pragma unroll
                for (int jt = 0; jt < 4; ++jt) {
                    float p = __expf(s_t[jt][r] - m_new);
                    s_t[jt][r] = p;
                    rs += p;
                }
                l_[r] = l_[r] * alpha[r] + rs;
            }
            // P (C-layout) -> per-wave LDS region, XOR-swizzled (no barrier needed)
            #pragma unroll
            for (int jt = 0; jt < 4; ++jt)
                #pragma unroll
                for (int r = 0; r < 4; ++r) {
                    int prow = quad * 4 + r;
                    int inb  = (jt * 16 + l16) * 2;
                    *(__bf16*)(psw + prow * 128 + (inb ^ ((prow & 7) << 4))) =
                        (__bf16)s_t[jt][r];
                }
            #pragma unroll
            for (int dt = 0; dt < 8; ++dt)
                #pragma unroll
                for (int r = 0; r < 4; ++r) o_acc[dt][r] *= alpha[r];

            // P A-frags back from LDS; PV with V B-frags read from Vs[cur]
            int rb  = l16 * 128;
            int swz = (l16 & 7) << 4;
            bf16x8 p0 = *(bf16x8*)(psw + rb + ((quad * 16) ^ swz));
            bf16x8 p1 = *(bf16x8*)(psw + rb + ((64 + quad * 16) ^ swz));
            #pragma unroll
            for (int dt = 0; dt < 8; ++dt) {
                bf16x8 vf0 = *(bf16x8*)&Vs[cur][(dt * 2 + 0) * 512 + lane * 8];
                bf16x8 vf1 = *(bf16x8*)&Vs[cur][(dt * 2 + 1) * 512 + lane * 8];
                o_acc[dt] = __builtin_amdgcn_mfma_f32_16x16x32_bf16(
                    p0, vf0, o_acc[dt], 0, 0, 0);
                o_acc[dt] = __builtin_amdgcn_mfma_f32_16x16x32_bf16(
                    p1, vf1, o_acc[dt], 0, 0, 0);
            }
        }

        // deferred l reduction (DPP) + normalize + store
        float invl[4];
        #pragma unroll
        for (int r = 0; r < 4; ++r) invl[r] = 1.f / rowsum16(l_[r]);
        size_t obase = ((size_t)b * S + q0 + wave * 16 + quad * 4) * 2048
                       + h * 128 + l16;
        #pragma unroll
        for (int dt = 0; dt < 8; ++dt)
            #pragma unroll
            for (int r = 0; r < 4; ++r)
                vo[obase + (size_t)r * 2048 + dt * 16] = (__bf16)(o_acc[dt][r] * invl[r]);
    }
}

// ---------------------------------------------------------------- launch

extern "C" void kernel_launch(void* const* d_in, const int* in_sizes, int n_in,
                              void* d_out, int out_size, void* d_ws, size_t ws_size,
                              hipStream_t stream) {
    const float* x    = (const float*)d_in[0];
    const float* cosp = (const float*)d_in[1];
    const float* sinp = (const float*)d_in[2];
    const float* Wq   = (const float*)d_in[3];
    const float* bq   = (const float*)d_in[4];
    const float* Wkv  = (const float*)d_in[5];
    const float* bkv  = (const float*)d_in[6];
    const float* Wo   = (const float*)d_in[7];
    const float* bo   = (const float*)d_in[8];
    const int* causal = (const int*)d_in[9];
    float* out = (float*)d_out;

    const int B = 2, S = 2048;
    const int M = B * S;  // 4096

    // workspace layout (~60 MB)
    char* w = (char*)d_ws;
    __bf16* x16    = (__bf16*)w; w += (size_t)M * 2048 * 2;     // 16 MB; later = vobuf
    __bf16* Wqkvt  = (__bf16*)w; w += (size_t)3072 * 2048 * 2;  // 12 MB; later = vtg
    __bf16* Wot    = (__bf16*)w; w += (size_t)2048 * 2048 * 2;  //  8 MB
    float*  bqkv   = (float*)w;  w += (size_t)3072 * 4;         // 12 KB
    __bf16* qkvbuf = (__bf16*)w; w += (size_t)M * 3072 * 2;     // 24 MB
    __bf16* vobuf  = x16;    // alias: x16 dead after fused GEMM
    __bf16* vtg    = Wqkvt;  // alias: Wqkvt dead after fused GEMM (4 MB <= 12 MB)

    f32_to_bf16_kernel<<<(M * 2048) / (256 * 8), 256, 0, stream>>>(x, x16, (size_t)M * 2048);
    // fused weight: Wqkvt rows 0..2047 = Wq^T, rows 2048..3071 = Wkv^T
    transpose_to_bf16_kernel<<<dim3(2048 / 32, 2048 / 32), dim3(32, 8), 0, stream>>>(Wq, Wqkvt, 2048, 2048);
    transpose_to_bf16_kernel<<<dim3(1024 / 32, 2048 / 32), dim3(32, 8), 0, stream>>>(Wkv, Wqkvt + (size_t)2048 * 2048, 2048, 1024);
    transpose_to_bf16_kernel<<<dim3(2048 / 32, 2048 / 32), dim3(32, 8), 0, stream>>>(Wo, Wot, 2048, 2048);
    concat_bias_kernel<<<12, 256, 0, stream>>>(bq, bkv, bqkv);
    // fused QKV projection: [4096][3072], 1D grid 768 (%8==0) + XCD swizzle
    gemm_bt_bias_kernel<__bf16><<<dim3((M / BM) * (3072 / BN)), 256, 0, stream>>>(x16, Wqkvt, bqkv, qkvbuf, M, 3072, 2048);
    // RoPE on q (16 heads, col 0) and k (4 heads, col 2048)
    {
        int totq = M * 16 * 64;
        rope_kernel<<<(totq + 255) / 256, 256, 0, stream>>>(qkvbuf, cosp, sinp, 16, 3072, 0, S, totq);
        int totk = M * 4 * 64;
        rope_kernel<<<(totk + 255) / 256, 256, 0, stream>>>(qkvbuf, cosp, sinp, 4, 3072, 2048, S, totk);
    }
    // V -> dim-major global layout
    transpose_v_kernel<<<dim3(S / 32, 128 / 32, B * 4), dim3(32, 8), 0, stream>>>(qkvbuf, vtg, S);
    // 512 blocks: id%8 -> (b,kvh); paired Q-tiles -> uniform 33 walls/block
    flash_mfma_kernel<<<dim3(512), 256, 0, stream>>>(qkvbuf, vtg, vobuf, causal, S);
    // output projection (fp32 out), 1D grid 512 (%8==0) + XCD swizzle
    gemm_bt_bias_kernel<float><<<dim3((M / BM) * (2048 / BN)), 256, 0, stream>>>(vobuf, Wot, bo, out, M, 2048, 2048);
}

// Round 10
// 371.449 us; speedup vs baseline: 2.9737x; 1.0584x over previous
//
#include <hip/hip_runtime.h>
#include <hip/hip_bf16.h>

typedef __bf16 bf16x8 __attribute__((ext_vector_type(8)));
typedef float  f32x4  __attribute__((ext_vector_type(4)));
typedef unsigned int u32;

// async global->LDS, 16B/lane; LDS dest = wave-uniform base + lane*16 (m97/m104)
// global SOURCE is per-lane (guide m173) — used for both K and V staging.
#define GLD_LDS16(gp, lp) __builtin_amdgcn_global_load_lds( \
    (const __attribute__((address_space(1))) u32*)(gp), \
    (__attribute__((address_space(3))) u32*)(lp), 16, 0, 0)

// DPP cyclic rotate within 16-lane rows (row_ror:N = 0x120|N)
template<int CTRL>
__device__ __forceinline__ float dpp_rot(float x) {
    int y = __builtin_amdgcn_update_dpp(__float_as_int(x), __float_as_int(x),
                                        CTRL, 0xF, 0xF, false);
    return __int_as_float(y);
}
__device__ __forceinline__ float rowmax16(float x) {
    x = fmaxf(x, dpp_rot<0x121>(x));
    x = fmaxf(x, dpp_rot<0x122>(x));
    x = fmaxf(x, dpp_rot<0x124>(x));
    x = fmaxf(x, dpp_rot<0x128>(x));
    return x;
}
__device__ __forceinline__ float rowsum16(float x) {
    x += dpp_rot<0x121>(x);
    x += dpp_rot<0x122>(x);
    x += dpp_rot<0x124>(x);
    x += dpp_rot<0x128>(x);
    return x;
}

// ---------------------------------------------------------------- fused prep
// ONE launch replacing: f32->bf16(x), Wq^T, Wkv^T, Wo^T, bias concat.
// blockIdx.x range dispatch; branch is block-uniform so per-job barriers are
// safe (no block mixes jobs).
#define NPREP_A 4096   // x convert: (4096*2048)/(256*8)
#define NPREP_B 4096   // Wq^T  (2048x2048, 32x32 tiles: 64x64)
#define NPREP_C 2048   // Wkv^T (2048x1024: 32 n-tiles x 64 k-tiles)
#define NPREP_D 4096   // Wo^T  (2048x2048)
#define NPREP_E 12     // bias concat (3072 elems)

__global__ __launch_bounds__(256) void prep_kernel(
    const float* __restrict__ x, __bf16* __restrict__ x16,
    const float* __restrict__ Wq, const float* __restrict__ Wkv,
    const float* __restrict__ Wo,
    __bf16* __restrict__ Wqkvt, __bf16* __restrict__ Wot,
    const float* __restrict__ bq, const float* __restrict__ bkv,
    float* __restrict__ bqkv) {
    __shared__ float tile[32][33];
    int bid = blockIdx.x;
    int tid = threadIdx.x;

    if (bid < NPREP_A) {                       // ---- x f32 -> bf16
        size_t i = (size_t)bid * 2048 + tid * 8;
        float4 a = *(const float4*)(x + i);
        float4 b = *(const float4*)(x + i + 4);
        bf16x8 v;
        v[0] = (__bf16)a.x; v[1] = (__bf16)a.y; v[2] = (__bf16)a.z; v[3] = (__bf16)a.w;
        v[4] = (__bf16)b.x; v[5] = (__bf16)b.y; v[6] = (__bf16)b.z; v[7] = (__bf16)b.w;
        *(bf16x8*)(x16 + i) = v;
        return;
    }
    bid -= NPREP_A;
    int tx = tid & 31, ty = tid >> 5;          // 32 x 8 for transposes

    if (bid < NPREP_B) {                       // ---- Wq^T -> Wqkvt rows 0..2047
        int n0 = (bid & 63) * 32, k0 = (bid >> 6) * 32;
        #pragma unroll
        for (int i = 0; i < 32; i += 8)
            tile[ty + i][tx] = Wq[(size_t)(k0 + ty + i) * 2048 + n0 + tx];
        __syncthreads();
        #pragma unroll
        for (int i = 0; i < 32; i += 8)
            Wqkvt[(size_t)(n0 + ty + i) * 2048 + k0 + tx] = (__bf16)tile[tx][ty + i];
        return;
    }
    bid -= NPREP_B;
    if (bid < NPREP_C) {                       // ---- Wkv^T -> Wqkvt rows 2048..3071
        int n0 = (bid & 31) * 32, k0 = (bid >> 5) * 32;
        #pragma unroll
        for (int i = 0; i < 32; i += 8)
            tile[ty + i][tx] = Wkv[(size_t)(k0 + ty + i) * 1024 + n0 + tx];
        __syncthreads();
        #pragma unroll
        for (int i = 0; i < 32; i += 8)
            Wqkvt[(size_t)(2048 + n0 + ty + i) * 2048 + k0 + tx] = (__bf16)tile[tx][ty + i];
        return;
    }
    bid -= NPREP_C;
    if (bid < NPREP_D) {                       // ---- Wo^T -> Wot
        int n0 = (bid & 63) * 32, k0 = (bid >> 6) * 32;
        #pragma unroll
        for (int i = 0; i < 32; i += 8)
            tile[ty + i][tx] = Wo[(size_t)(k0 + ty + i) * 2048 + n0 + tx];
        __syncthreads();
        #pragma unroll
        for (int i = 0; i < 32; i += 8)
            Wot[(size_t)(n0 + ty + i) * 2048 + k0 + tx] = (__bf16)tile[tx][ty + i];
        return;
    }
    bid -= NPREP_D;
    {                                          // ---- bias concat
        int i = bid * 256 + tid;
        if (i < 2048) bqkv[i] = bq[i];
        else if (i < 3072) bqkv[i] = bkv[i - 2048];
    }
}

// ---------------------------------------------------------------- GEMM (m97: BK=64)
// MODE 0: plain fp32-out store (output projection).
// MODE 1: QKV projection with fused epilogue — bn<16: rope'd q -> qkvbuf;
//   16<=bn<20: rope'd k -> qkvbuf; 20<=bn<24: V transposed -> vtg (v never
//   touches qkvbuf; qkvbuf row stride CS=2560). Epilogue stages acc+bias as
//   bf16 in a 128x136 LDS tile (re-using staging LDS, barriered) for the
//   cross-wave (d, d+64) pairing rope needs. Numerics identical to the old
//   separate rope kernel (same bf16 rounding point).
// NOTE: vtg must NOT alias Wqkvt (B operand is read all kernel long) — it
// has its own workspace slot now.
#define BM 128
#define BN 128
#define BK 64

template <typename OutT, int MODE>
__global__ __launch_bounds__(256) void gemm_bt_bias_kernel(
    const __bf16* __restrict__ A, const __bf16* __restrict__ Bt,
    const float* __restrict__ bias, OutT* __restrict__ C,
    int M, int N, int K, int CS,
    const float* __restrict__ cosp, const float* __restrict__ sinp,
    __bf16* __restrict__ vtg, int S) {
    __shared__ __align__(16) char smem[MODE ? (128 * 136 * 2) : (2 * BM * BK * 2)];
    __bf16* As = (__bf16*)smem;
    __bf16* Bs = As + BM * BK;
    int tid  = threadIdx.x;
    // XCD swizzle: contiguous chunk per XCD; within chunk bm-major
    int nwg  = gridDim.x;
    int cpx  = nwg >> 3;
    int swzb = (blockIdx.x & 7) * cpx + (blockIdx.x >> 3);
    int nbm  = M / BM;
    int bm   = swzb % nbm;
    int bn   = swzb / nbm;
    int wave = tid >> 6;
    int lane = tid & 63;
    int wm   = (wave >> 1) * 64;
    int wn   = (wave & 1) * 64;
    int quad = lane >> 4;
    int l16  = lane & 15;
    int gr   = wave * 32 + (lane >> 3);
    int gc   = (lane & 7) * 8;

    f32x4 acc[4][4];
    f32x4 zero = {0.f, 0.f, 0.f, 0.f};
    #pragma unroll
    for (int i = 0; i < 4; ++i)
        #pragma unroll
        for (int j = 0; j < 4; ++j) acc[i][j] = zero;

    const __bf16* Abase = A  + (size_t)(bm * BM) * K;
    const __bf16* Bbase = Bt + (size_t)(bn * BN) * K;

    for (int k0 = 0; k0 < K; k0 += BK) {
        if (k0) __syncthreads();
        #pragma unroll
        for (int i = 0; i < 4; ++i) {
            GLD_LDS16(Abase + (size_t)(gr + i * 8) * K + k0 + gc,
                      &As[(wave * 32 + i * 8) * BK]);
            GLD_LDS16(Bbase + (size_t)(gr + i * 8) * K + k0 + gc,
                      &Bs[(wave * 32 + i * 8) * BK]);
        }
        __syncthreads();

        bf16x8 af[4][2], bf[4][2];
        #pragma unroll
        for (int i = 0; i < 4; ++i)
            #pragma unroll
            for (int kc = 0; kc < 2; ++kc)
                af[i][kc] = *(bf16x8*)&As[(wm + i * 16 + l16) * BK + kc * 32 + quad * 8];
        #pragma unroll
        for (int j = 0; j < 4; ++j)
            #pragma unroll
            for (int kc = 0; kc < 2; ++kc)
                bf[j][kc] = *(bf16x8*)&Bs[(wn + j * 16 + l16) * BK + kc * 32 + quad * 8];
        #pragma unroll
        for (int kc = 0; kc < 2; ++kc)
            #pragma unroll
            for (int i = 0; i < 4; ++i)
                #pragma unroll
                for (int j = 0; j < 4; ++j)
                    acc[i][j] = __builtin_amdgcn_mfma_f32_16x16x32_bf16(
                        af[i][kc], bf[j][kc], acc[i][j], 0, 0, 0);
    }

    if constexpr (MODE == 0) {
        // D layout (HW-verified m89/m91): row = quad*4+reg, col = l16
        #pragma unroll
        for (int i = 0; i < 4; ++i) {
            int row = bm * BM + wm + i * 16 + quad * 4;
            #pragma unroll
            for (int j = 0; j < 4; ++j) {
                int col  = bn * BN + wn + j * 16 + l16;
                float bv = bias[col];
                #pragma unroll
                for (int r = 0; r < 4; ++r)
                    C[(size_t)(row + r) * N + col] = (OutT)(acc[i][j][r] + bv);
            }
        }
    } else {
        // ---- fused epilogue: stage acc+bias (bf16) in LDS for cross-wave pairing
        __syncthreads();  // all waves done with staging LDS reads
        __bf16 (*tile)[136] = (__bf16 (*)[136])smem;
        #pragma unroll
        for (int i = 0; i < 4; ++i) {
            int rr = wm + i * 16 + quad * 4;
            #pragma unroll
            for (int j = 0; j < 4; ++j) {
                int cc = wn + j * 16 + l16;
                float bv = bias[bn * BN + cc];
                #pragma unroll
                for (int r = 0; r < 4; ++r)
                    tile[rr + r][cc] = (__bf16)(acc[i][j][r] + bv);
            }
        }
        __syncthreads();

        if (bn < 20) {
            // rope'd q/k -> qkvbuf (head-aligned 128-col tile; global col = bn*128)
            #pragma unroll
            for (int p = 0; p < 4; ++p) {
                int sr = p * 32 + (tid >> 3);
                int d0 = (tid & 7) * 8;
                int grow = bm * BM + sr;
                int s = grow & (S - 1);
                const float* cp = cosp + (size_t)s * 64 + d0;
                const float* sp = sinp + (size_t)s * 64 + d0;
                bf16x8 r1, r2;
                #pragma unroll
                for (int e = 0; e < 8; ++e) {
                    float x1 = (float)tile[sr][d0 + e];
                    float x2 = (float)tile[sr][64 + d0 + e];
                    float c = cp[e], sn = sp[e];
                    r1[e] = (__bf16)(x1 * c - x2 * sn);
                    r2[e] = (__bf16)(x1 * sn + x2 * c);
                }
                __bf16* outp = (__bf16*)C + (size_t)grow * CS + bn * BN + d0;
                *(bf16x8*)(outp)      = r1;
                *(bf16x8*)(outp + 64) = r2;
            }
        } else {
            // V transposed -> vtg[(b*4+kvh)*128 + d][s]
            int kvh = bn - 20;
            int d  = tid & 127, sg = tid >> 7;
            #pragma unroll
            for (int p = 0; p < 8; ++p) {
                int sl = (p * 2 + sg) * 8;
                bf16x8 v;
                #pragma unroll
                for (int si = 0; si < 8; ++si) v[si] = tile[sl + si][d];
                int grow = bm * BM + sl;
                int b = grow >> 11;           // S = 2048
                int s = grow & (S - 1);
                *(bf16x8*)&vtg[((size_t)(b * 4 + kvh) * 128 + d) * S + s] = v;
            }
        }
    }
}

// ---------------------------------------------------------------- MFMA flash attention
// r9-proven structure (114.4us): paired Q-tiles, K AND V staged through LDS
// via zero-VGPR global_load_lds double-buffers, per-wave XOR-swizzled Ps,
// DPP softmax with deferred l-reduce. Round-10 deltas: QKV row stride 2560
// (v cols dropped from qkvbuf) + T5 setprio around both MFMA clusters
// (2 blocks/CU = wave role diversity; m191 +4-7%).
// Tripwires: VGPR ~104, WRITE_SIZE 16384 KB, LDS 73728, bank conflicts ~0.

__global__ __launch_bounds__(256) void flash_mfma_kernel(
    const __bf16* __restrict__ qkv,  // [B*S][2560]: q(0..2047)|k(2048..2559)
    const __bf16* __restrict__ vtg,  // [(b*4+kvh)*128 + d][S]
    __bf16* __restrict__ vo,         // [B*S][2048]
    const int* __restrict__ causal_p, int S) {
    __shared__ __bf16 Ks[2][64 * 128];
    __shared__ __bf16 Vs[2][64 * 128];
    __shared__ __bf16 Ps[4 * 16 * 64];

    const int QKV = 2560;
    int tid  = threadIdx.x;
    int wave = tid >> 6;
    int lane = tid & 63;
    int quad = lane >> 4;
    int l16  = lane & 15;
    int id   = blockIdx.x;
    int xcd  = id & 7;           // id%8 -> (b,kvh): XCD L2 affinity (MODE4-verified)
    int b    = xcd >> 2;
    int kvh  = xcd & 3;
    int rest = id >> 3;
    int hh   = rest & 3;
    int pair = rest >> 2;
    int h    = kvh * 4 + hh;
    int causal = causal_p[0];
    const float SCALE = 0.08838834764831845f;  // 1/sqrt(128)

    const __bf16* vB = vtg + ((size_t)(b * 4 + kvh) * 128) * S;
    char* psw = (char*)Ps + wave * 2048;

    #pragma unroll 1
    for (int phase = 0; phase < 2; ++phase) {
        int qt = phase ? (31 - pair) : pair;
        int q0 = qt * 64;
        int nt = causal ? (qt + 1) : (S / 64);

        bf16x8 a_frag[4];
        size_t qrow = ((size_t)b * S + q0 + wave * 16 + l16) * QKV + h * 128 + quad * 8;
        #pragma unroll
        for (int kc = 0; kc < 4; ++kc)
            a_frag[kc] = *(const bf16x8*)(qkv + qrow + kc * 32);

        f32x4 o_acc[8];
        f32x4 zero4 = {0.f, 0.f, 0.f, 0.f};
        #pragma unroll
        for (int dt = 0; dt < 8; ++dt) o_acc[dt] = zero4;
        float m_[4], l_[4];
        #pragma unroll
        for (int r = 0; r < 4; ++r) { m_[r] = -1e30f; l_[r] = 0.f; }
        int qrow_d = q0 + wave * 16 + quad * 4;

        __syncthreads();  // protect Ks/Vs from previous phase's readers
        {
            size_t kg = ((size_t)b * S + wave * 16 + l16) * QKV + 2048 + kvh * 128 + quad * 8;
            #pragma unroll
            for (int kc = 0; kc < 4; ++kc)
                GLD_LDS16(qkv + kg + kc * 32, &Ks[0][(wave * 4 + kc) * 512]);
            #pragma unroll
            for (int i = 0; i < 4; ++i) {
                int c  = wave * 4 + i;       // chunk: dt = c>>1, kc = c&1
                int dt = c >> 1, kc = c & 1;
                GLD_LDS16(vB + (size_t)(dt * 16 + l16) * S + kc * 32 + quad * 8,
                          &Vs[0][c * 512]);
            }
        }

        for (int t = 0; t < nt; ++t) {
            int cur = t & 1;
            __syncthreads();  // drains vmcnt: K(t)+V(t) DMA complete
            if (t + 1 < nt) {
                size_t kg = ((size_t)b * S + (t + 1) * 64 + wave * 16 + l16) * QKV
                            + 2048 + kvh * 128 + quad * 8;
                #pragma unroll
                for (int kc = 0; kc < 4; ++kc)
                    GLD_LDS16(qkv + kg + kc * 32, &Ks[1 - cur][(wave * 4 + kc) * 512]);
                size_t vgoff = (size_t)(t + 1) * 64;
                #pragma unroll
                for (int i = 0; i < 4; ++i) {
                    int c  = wave * 4 + i;
                    int dt = c >> 1, kc = c & 1;
                    GLD_LDS16(vB + (size_t)(dt * 16 + l16) * S + vgoff + kc * 32 + quad * 8,
                              &Vs[1 - cur][c * 512]);
                }
            }
            int j0 = t * 64;

            // S = Q @ K^T
            f32x4 s_t[4];
            #pragma unroll
            for (int jt = 0; jt < 4; ++jt) s_t[jt] = zero4;
            __builtin_amdgcn_s_setprio(1);
            #pragma unroll
            for (int jt = 0; jt < 4; ++jt)
                #pragma unroll
                for (int kc = 0; kc < 4; ++kc) {
                    bf16x8 kf = *(bf16x8*)&Ks[cur][(jt * 4 + kc) * 512 + lane * 8];
                    s_t[jt] = __builtin_amdgcn_mfma_f32_16x16x32_bf16(
                        a_frag[kc], kf, s_t[jt], 0, 0, 0);
                }
            __builtin_amdgcn_s_setprio(0);

            int diag = causal && (t == nt - 1);
            #pragma unroll
            for (int jt = 0; jt < 4; ++jt)
                #pragma unroll
                for (int r = 0; r < 4; ++r) {
                    float sv = s_t[jt][r] * SCALE;
                    if (diag && (j0 + jt * 16 + l16 > qrow_d + r)) sv = -1e30f;
                    s_t[jt][r] = sv;
                }

            float alpha[4];
            #pragma unroll
            for (int r = 0; r < 4; ++r) {
                float v = fmaxf(fmaxf(s_t[0][r], s_t[1][r]),
                                fmaxf(s_t[2][r], s_t[3][r]));
                v = rowmax16(v);
                float m_new = fmaxf(m_[r], v);
                alpha[r] = __expf(m_[r] - m_new);
                m_[r] = m_new;
                float rs = 0.f;
                #pragma unroll
                for (int jt = 0; jt < 4; ++jt) {
                    float p = __expf(s_t[jt][r] - m_new);
                    s_t[jt][r] = p;
                    rs += p;
                }
                l_[r] = l_[r] * alpha[r] + rs;
            }
            #pragma unroll
            for (int jt = 0; jt < 4; ++jt)
                #pragma unroll
                for (int r = 0; r < 4; ++r) {
                    int prow = quad * 4 + r;
                    int inb  = (jt * 16 + l16) * 2;
                    *(__bf16*)(psw + prow * 128 + (inb ^ ((prow & 7) << 4))) =
                        (__bf16)s_t[jt][r];
                }
            #pragma unroll
            for (int dt = 0; dt < 8; ++dt)
                #pragma unroll
                for (int r = 0; r < 4; ++r) o_acc[dt][r] *= alpha[r];

            int rb  = l16 * 128;
            int swz = (l16 & 7) << 4;
            bf16x8 p0 = *(bf16x8*)(psw + rb + ((quad * 16) ^ swz));
            bf16x8 p1 = *(bf16x8*)(psw + rb + ((64 + quad * 16) ^ swz));
            __builtin_amdgcn_s_setprio(1);
            #pragma unroll
            for (int dt = 0; dt < 8; ++dt) {
                bf16x8 vf0 = *(bf16x8*)&Vs[cur][(dt * 2 + 0) * 512 + lane * 8];
                bf16x8 vf1 = *(bf16x8*)&Vs[cur][(dt * 2 + 1) * 512 + lane * 8];
                o_acc[dt] = __builtin_amdgcn_mfma_f32_16x16x32_bf16(
                    p0, vf0, o_acc[dt], 0, 0, 0);
                o_acc[dt] = __builtin_amdgcn_mfma_f32_16x16x32_bf16(
                    p1, vf1, o_acc[dt], 0, 0, 0);
            }
            __builtin_amdgcn_s_setprio(0);
        }

        float invl[4];
        #pragma unroll
        for (int r = 0; r < 4; ++r) invl[r] = 1.f / rowsum16(l_[r]);
        size_t obase = ((size_t)b * S + q0 + wave * 16 + quad * 4) * 2048
                       + h * 128 + l16;
        #pragma unroll
        for (int dt = 0; dt < 8; ++dt)
            #pragma unroll
            for (int r = 0; r < 4; ++r)
                vo[obase + (size_t)r * 2048 + dt * 16] = (__bf16)(o_acc[dt][r] * invl[r]);
    }
}

// ---------------------------------------------------------------- launch

extern "C" void kernel_launch(void* const* d_in, const int* in_sizes, int n_in,
                              void* d_out, int out_size, void* d_ws, size_t ws_size,
                              hipStream_t stream) {
    const float* x    = (const float*)d_in[0];
    const float* cosp = (const float*)d_in[1];
    const float* sinp = (const float*)d_in[2];
    const float* Wq   = (const float*)d_in[3];
    const float* bq   = (const float*)d_in[4];
    const float* Wkv  = (const float*)d_in[5];
    const float* bkv  = (const float*)d_in[6];
    const float* Wo   = (const float*)d_in[7];
    const float* bo   = (const float*)d_in[8];
    const int* causal = (const int*)d_in[9];
    float* out = (float*)d_out;

    const int B = 2, S = 2048;
    const int M = B * S;  // 4096

    // workspace layout (~61 MB). NOTE: vtg is its OWN slot (must not alias
    // Wqkvt — GEMM1 reads Wqkvt while its epilogue writes vtg).
    char* w = (char*)d_ws;
    __bf16* x16    = (__bf16*)w; w += (size_t)M * 2048 * 2;     // 16 MB; later = vobuf
    __bf16* Wqkvt  = (__bf16*)w; w += (size_t)3072 * 2048 * 2;  // 12 MB
    __bf16* Wot    = (__bf16*)w; w += (size_t)2048 * 2048 * 2;  //  8 MB
    float*  bqkv   = (float*)w;  w += (size_t)3072 * 4;         // 12 KB
    __bf16* qkvbuf = (__bf16*)w; w += (size_t)M * 2560 * 2;     // 21 MB (q|k only)
    __bf16* vtg    = (__bf16*)w; w += (size_t)8 * 128 * S * 2;  //  4 MB
    __bf16* vobuf  = x16;    // alias: x16 dead after fused GEMM

    // 1) fused prep (5 jobs in one launch)
    prep_kernel<<<dim3(NPREP_A + NPREP_B + NPREP_C + NPREP_D + NPREP_E), 256, 0, stream>>>(
        x, x16, Wq, Wkv, Wo, Wqkvt, Wot, bq, bkv, bqkv);
    // 2) fused QKV projection + RoPE + V-transpose (768 blocks, XCD swizzle)
    gemm_bt_bias_kernel<__bf16, 1><<<dim3((M / BM) * (3072 / BN)), 256, 0, stream>>>(
        x16, Wqkvt, bqkv, qkvbuf, M, 3072, 2048, 2560, cosp, sinp, vtg, S);
    // 3) flash attention (512 blocks: id%8 -> (b,kvh); paired Q-tiles)
    flash_mfma_kernel<<<dim3(512), 256, 0, stream>>>(qkvbuf, vtg, vobuf, causal, S);
    // 4) output projection (fp32 out, 512 blocks, XCD swizzle)
    gemm_bt_bias_kernel<float, 0><<<dim3((M / BM) * (2048 / BN)), 256, 0, stream>>>(
        vobuf, Wot, bo, out, M, 2048, 2048, 2048, nullptr, nullptr, nullptr, S);
}